// Round 4
// baseline (276.151 us; speedup 1.0000x reference)
//
#include <hip/hip_runtime.h>

// Problem constants
#define CIN  1024
#define COUT 1024
#define LB   2048
#define BB   8

// Algebraic collapse: softmax over attns[b,q,k] = fcq[b,q] + fck[b,k] is
// independent of q (per-row constant cancels), so weights p[b,k] =
// softmax_k(key[b,k,:].u) with u = Wk^T fck_w (bias cancels too), and
// out[b,q,:] = (sum_k p[b,k] value[b,k,:]) . Wv^T + bv  -- same row for all q.
// Scores are tiny (|s| <~ 2, sigma ~ 0.33) so no max-subtraction is needed:
// accumulate num = sum_k exp(s_k) v_k and den = sum_k exp(s_k) directly (fp32).
//
// ws float layout:
//   u    : [0, 1024)        u[c] = sum_o fck_w[o] * Wk[o,c]        (atomic, memset)
//   num  : [1024, 9216)     num[b,c] = sum_k e[b,k] value[b,k,c]   (atomic, memset)
//   den  : [9216, 9224)     den[b]   = sum_k e[b,k]                (atomic, memset)
//   e    : [9224, 25608)    e[b*L+k] = exp(key[b,k,:].u)
//   orow : [25608, 33800)   orow[b,d] = num[b,:].Wv[d,:]/den[b] + bv[d]

// u[c] = sum_o fckw[o]*Wk[o,c].  64 blocks = 4 c-chunks x 16 o-chunks.
__global__ __launch_bounds__(256) void k_u(const float* __restrict__ Wk,
                                           const float* __restrict__ fckw,
                                           float* __restrict__ u) {
    __shared__ float4 red[256];
    const float4* Wk4 = (const float4*)Wk;   // rows of 256 float4
    int t = threadIdx.x;
    int cc = blockIdx.x & 3;                 // c-chunk of 256 floats (64 float4)
    int oc = blockIdx.x >> 2;                // o-chunk of 64 rows
    int c4 = cc * 64 + (t & 63);
    int w  = t >> 6;
    float4 acc = make_float4(0.f, 0.f, 0.f, 0.f);
    #pragma unroll
    for (int j = 0; j < 16; ++j) {
        int o = oc * 64 + w + j * 4;
        float f = fckw[o];
        float4 a = Wk4[(size_t)o * 256 + c4];
        acc.x += f * a.x; acc.y += f * a.y; acc.z += f * a.z; acc.w += f * a.w;
    }
    red[t] = acc;
    __syncthreads();
    if (t < 64) {
        float4 a = red[t], b = red[t + 64], c = red[t + 128], d = red[t + 192];
        float4 s;
        s.x = a.x + b.x + c.x + d.x;
        s.y = a.y + b.y + c.y + d.y;
        s.z = a.z + b.z + c.z + d.z;
        s.w = a.w + b.w + c.w + d.w;
        float* up = u + (size_t)cc * 256 + t * 4;
        atomicAdd(up + 0, s.x);
        atomicAdd(up + 1, s.y);
        atomicAdd(up + 2, s.z);
        atomicAdd(up + 3, s.w);
    }
}

// e[r] = exp(key[r,:].u), den[b] += block partial sum.  4096 blocks, wave/row.
__global__ __launch_bounds__(256) void k_scores(const float* __restrict__ key,
                                                const float* __restrict__ u,
                                                float* __restrict__ e,
                                                float* __restrict__ den) {
    __shared__ float su[CIN];
    __shared__ float se[4];
    int tid = threadIdx.x;
    ((float4*)su)[tid] = ((const float4*)u)[tid];
    __syncthreads();
    int wave = tid >> 6, lane = tid & 63;
    int r = blockIdx.x * 4 + wave;           // 4 rows/block, same batch (512 blk/batch)
    const float4* row = (const float4*)(key + (size_t)r * CIN);
    const float4* su4 = (const float4*)su;
    float acc = 0.f;
    #pragma unroll
    for (int j = 0; j < 4; ++j) {
        float4 a = row[lane + j * 64];
        float4 b = su4[lane + j * 64];
        acc += a.x * b.x + a.y * b.y + a.z * b.z + a.w * b.w;
    }
    #pragma unroll
    for (int off = 32; off; off >>= 1) acc += __shfl_down(acc, off, 64);
    if (lane == 0) {
        float ex = __expf(acc);
        e[r] = ex;
        se[wave] = ex;
    }
    __syncthreads();
    if (tid == 0)
        atomicAdd(&den[blockIdx.x >> 9], se[0] + se[1] + se[2] + se[3]);
}

// num[b,c] += sum_{k in chunk} e[b,k]*value[b,k,c].  512 blocks = 8 b x 64 chunks(32).
__global__ __launch_bounds__(256) void k_vbar(const float* __restrict__ value,
                                              const float* __restrict__ e,
                                              float* __restrict__ num) {
    __shared__ float el[32];
    int t = threadIdx.x;
    int b  = blockIdx.x >> 6;
    int k0 = (blockIdx.x & 63) * 32;
    if (t < 32) el[t] = e[(size_t)b * LB + k0 + t];
    __syncthreads();
    const float4* v4 = (const float4*)value + ((size_t)b * LB + k0) * 256 + t;
    float4 acc = make_float4(0.f, 0.f, 0.f, 0.f);
    #pragma unroll 8
    for (int k = 0; k < 32; ++k) {
        float pw = el[k];
        float4 a = v4[(size_t)k * 256];
        acc.x += pw * a.x; acc.y += pw * a.y; acc.z += pw * a.z; acc.w += pw * a.w;
    }
    float* np = num + (size_t)b * CIN + t * 4;
    atomicAdd(np + 0, acc.x);
    atomicAdd(np + 1, acc.y);
    atomicAdd(np + 2, acc.z);
    atomicAdd(np + 3, acc.w);
}

// orow[r] = num[b,:].Wv[d,:]/den[b] + bv[d]   (r = b*COUT+d). 4 rows/block.
__global__ __launch_bounds__(256) void k_orow(const float* __restrict__ Wv,
                                              const float* __restrict__ bv,
                                              const float* __restrict__ num,
                                              const float* __restrict__ den,
                                              float* __restrict__ orow) {
    __shared__ float sv[CIN];
    int tid = threadIdx.x;
    int r0 = blockIdx.x * 4;
    int b = r0 >> 10;
    ((float4*)sv)[tid] = ((const float4*)(num + (size_t)b * CIN))[tid];
    __syncthreads();
    int wave = tid >> 6, lane = tid & 63;
    int r = r0 + wave;
    int d = r & 1023;
    const float4* row = (const float4*)(Wv + (size_t)d * CIN);
    const float4* sv4 = (const float4*)sv;
    float acc = 0.f;
    #pragma unroll
    for (int j = 0; j < 4; ++j) {
        float4 a = row[lane + j * 64];
        float4 v = sv4[lane + j * 64];
        acc += a.x * v.x + a.y * v.y + a.z * v.z + a.w * v.w;
    }
    #pragma unroll
    for (int off = 32; off; off >>= 1) acc += __shfl_down(acc, off, 64);
    if (lane == 0) orow[r] = acc / den[b] + bv[d];
}

// out[b,q,:] = orow[b,:] for all q. One read + 8 row-stores per thread.
__global__ __launch_bounds__(256) void k_bcast(const float* __restrict__ orow,
                                               float* __restrict__ out) {
    int t = threadIdx.x;
    int b  = blockIdx.x >> 8;
    int q0 = (blockIdx.x & 255) * 8;
    float4 val = ((const float4*)orow)[b * 256 + t];
    float4* out4 = (float4*)out;
    #pragma unroll
    for (int j = 0; j < 8; ++j)
        out4[((size_t)b * LB + q0 + j) * 256 + t] = val;
}

extern "C" void kernel_launch(void* const* d_in, const int* in_sizes, int n_in,
                              void* d_out, int out_size, void* d_ws, size_t ws_size,
                              hipStream_t stream) {
    // inputs: 0 query, 1 key, 2 value, 3 Wq, 4 bq, 5 Wk, 6 bk, 7 Wv, 8 bv,
    //         9 fcq_w, 10 fcq_b, 11 fck_w, 12 fck_b
    const float* key   = (const float*)d_in[1];
    const float* value = (const float*)d_in[2];
    const float* Wk    = (const float*)d_in[5];
    const float* Wv    = (const float*)d_in[7];
    const float* bv    = (const float*)d_in[8];
    const float* fckw  = (const float*)d_in[11];

    float* ws   = (float*)d_ws;
    float* u    = ws;            // 1024
    float* num  = ws + 1024;     // 8192
    float* den  = ws + 9216;     // 8
    float* e    = ws + 9224;     // 16384
    float* orow = ws + 25608;    // 8192
    float* out  = (float*)d_out;

    // zero the atomic targets: u + num + den = 9224 floats (~37 KB)
    hipMemsetAsync(ws, 0, 9224 * sizeof(float), stream);

    hipLaunchKernelGGL(k_u,      dim3(64),   dim3(256), 0, stream, Wk, fckw, u);
    hipLaunchKernelGGL(k_scores, dim3(4096), dim3(256), 0, stream, key, u, e, den);
    hipLaunchKernelGGL(k_vbar,   dim3(512),  dim3(256), 0, stream, value, e, num);
    hipLaunchKernelGGL(k_orow,   dim3(2048), dim3(256), 0, stream, Wv, bv, num, den, orow);
    hipLaunchKernelGGL(k_bcast,  dim3(2048), dim3(256), 0, stream, orow, out);
}

// Round 5
// 244.154 us; speedup vs baseline: 1.1311x; 1.1311x over previous
//
#include <hip/hip_runtime.h>

// Problem constants
#define CIN  1024
#define COUT 1024
#define LB   2048
#define BB   8

// Algebraic collapse: softmax over attns[b,q,k] = fcq[b,q] + fck[b,k] is
// independent of q (per-row constant cancels), so weights p[b,k] =
// softmax_k(key[b,k,:].u) with u = Wk^T fck_w (bias cancels too), and
// out[b,q,:] = (sum_k p[b,k] value[b,k,:]) . Wv^T + bv  -- same row for all q.
// Scores are tiny (|s| <~ 2) so no max-subtraction: accumulate
// num = sum_k exp(s_k) v_k and den = sum_k exp(s_k) directly in fp32.
//
// ws float layout:
//   u    : [0, 1024)        u[c] = sum_o fck_w[o] * Wk[o,c]        (atomic, memset)
//   num  : [1024, 9216)     num[b,c] = sum_k e[b,k] value[b,k,c]   (atomic, memset)
//   den  : [9216, 9224)     den[b]   = sum_k e[b,k]                (atomic, memset)
//   e    : [9224, 25608)    e[b*L+k] = exp(key[b,k,:].u)
//   orow : [25608, 33800)   orow[b,d] = num[b,:].Wv[d,:]/den[b] + bv[d]

// u[c] = sum_o fckw[o]*Wk[o,c].  64 blocks = 4 c-chunks x 16 o-chunks.
__global__ __launch_bounds__(256) void k_u(const float* __restrict__ Wk,
                                           const float* __restrict__ fckw,
                                           float* __restrict__ u) {
    __shared__ float4 red[256];
    const float4* Wk4 = (const float4*)Wk;   // rows of 256 float4
    int t = threadIdx.x;
    int cc = blockIdx.x & 3;                 // c-chunk of 256 floats (64 float4)
    int oc = blockIdx.x >> 2;                // o-chunk of 64 rows
    int c4 = cc * 64 + (t & 63);
    int w  = t >> 6;
    float4 acc = make_float4(0.f, 0.f, 0.f, 0.f);
    #pragma unroll
    for (int j = 0; j < 16; ++j) {
        int o = oc * 64 + w + j * 4;
        float f = fckw[o];
        float4 a = Wk4[(size_t)o * 256 + c4];
        acc.x += f * a.x; acc.y += f * a.y; acc.z += f * a.z; acc.w += f * a.w;
    }
    red[t] = acc;
    __syncthreads();
    if (t < 64) {
        float4 a = red[t], b = red[t + 64], c = red[t + 128], d = red[t + 192];
        float4 s;
        s.x = a.x + b.x + c.x + d.x;
        s.y = a.y + b.y + c.y + d.y;
        s.z = a.z + b.z + c.z + d.z;
        s.w = a.w + b.w + c.w + d.w;
        float* up = u + (size_t)cc * 256 + t * 4;
        atomicAdd(up + 0, s.x);
        atomicAdd(up + 1, s.y);
        atomicAdd(up + 2, s.z);
        atomicAdd(up + 3, s.w);
    }
}

// e[r] = exp(key[r,:].u); den[b] += partials.
// 1024 blocks; block = 16-row x 1024-col tile; wave w = 256-col chunk with its
// u-segment in registers; 16 independent float4 loads in flight per lane.
__global__ __launch_bounds__(256) void k_scores(const float* __restrict__ key,
                                                const float* __restrict__ u,
                                                float* __restrict__ e,
                                                float* __restrict__ den) {
    __shared__ float sred[64];
    int t = threadIdx.x;
    int w = t >> 6, l = t & 63;
    int r0 = blockIdx.x * 16;
    float4 useg = ((const float4*)u)[w * 64 + l];
    const float4* k4 = (const float4*)key + (size_t)r0 * 256 + w * 64 + l;
    float part[16];
    #pragma unroll
    for (int j = 0; j < 16; ++j) {
        float4 a = k4[(size_t)j * 256];
        part[j] = a.x * useg.x + a.y * useg.y + a.z * useg.z + a.w * useg.w;
    }
    // 16 independent butterflies (ILP across rows; no serial bottleneck)
    #pragma unroll
    for (int j = 0; j < 16; ++j) {
        #pragma unroll
        for (int off = 32; off; off >>= 1)
            part[j] += __shfl_xor(part[j], off, 64);
    }
    if (l < 16) sred[w * 16 + l] = part[l];   // lane l: row l's chunk-sum
    __syncthreads();
    if (t < 16) {
        float s = sred[t] + sred[t + 16] + sred[t + 32] + sred[t + 48];
        float ex = __expf(s);
        e[r0 + t] = ex;
        float dsum = ex;
        #pragma unroll
        for (int off = 8; off; off >>= 1) dsum += __shfl_down(dsum, off, 16);
        if (t == 0) atomicAdd(&den[blockIdx.x >> 7], dsum);
    }
}

// num[b,c] += sum_{k in chunk} e[b,k]*value[b,k,c].  512 blocks = 8 b x 64 chunks(32).
__global__ __launch_bounds__(256) void k_vbar(const float* __restrict__ value,
                                              const float* __restrict__ e,
                                              float* __restrict__ num) {
    __shared__ float el[32];
    int t = threadIdx.x;
    int b  = blockIdx.x >> 6;
    int k0 = (blockIdx.x & 63) * 32;
    if (t < 32) el[t] = e[(size_t)b * LB + k0 + t];
    __syncthreads();
    const float4* v4 = (const float4*)value + ((size_t)b * LB + k0) * 256 + t;
    float4 acc = make_float4(0.f, 0.f, 0.f, 0.f);
    #pragma unroll 16
    for (int k = 0; k < 32; ++k) {
        float pw = el[k];
        float4 a = v4[(size_t)k * 256];
        acc.x += pw * a.x; acc.y += pw * a.y; acc.z += pw * a.z; acc.w += pw * a.w;
    }
    float* np = num + (size_t)b * CIN + t * 4;
    atomicAdd(np + 0, acc.x);
    atomicAdd(np + 1, acc.y);
    atomicAdd(np + 2, acc.z);
    atomicAdd(np + 3, acc.w);
}

// orow[r] = num[b,:].Wv[d,:]/den[b] + bv[d]   (r = b*COUT+d). 4 rows/block.
__global__ __launch_bounds__(256) void k_orow(const float* __restrict__ Wv,
                                              const float* __restrict__ bv,
                                              const float* __restrict__ num,
                                              const float* __restrict__ den,
                                              float* __restrict__ orow) {
    __shared__ float sv[CIN];
    int tid = threadIdx.x;
    int r0 = blockIdx.x * 4;
    int b = r0 >> 10;
    ((float4*)sv)[tid] = ((const float4*)(num + (size_t)b * CIN))[tid];
    __syncthreads();
    int wave = tid >> 6, lane = tid & 63;
    int r = r0 + wave;
    int d = r & 1023;
    const float4* row = (const float4*)(Wv + (size_t)d * CIN);
    const float4* sv4 = (const float4*)sv;
    float acc = 0.f;
    #pragma unroll
    for (int j = 0; j < 4; ++j) {
        float4 a = row[lane + j * 64];
        float4 v = sv4[lane + j * 64];
        acc += a.x * v.x + a.y * v.y + a.z * v.z + a.w * v.w;
    }
    #pragma unroll
    for (int off = 32; off; off >>= 1) acc += __shfl_down(acc, off, 64);
    if (lane == 0) orow[r] = acc / den[b] + bv[d];
}

// out[b,q,:] = orow[b,:] for all q. One read + 8 row-stores per thread.
__global__ __launch_bounds__(256) void k_bcast(const float* __restrict__ orow,
                                               float* __restrict__ out) {
    int t = threadIdx.x;
    int b  = blockIdx.x >> 8;
    int q0 = (blockIdx.x & 255) * 8;
    float4 val = ((const float4*)orow)[b * 256 + t];
    float4* out4 = (float4*)out;
    #pragma unroll
    for (int j = 0; j < 8; ++j)
        out4[((size_t)b * LB + q0 + j) * 256 + t] = val;
}

extern "C" void kernel_launch(void* const* d_in, const int* in_sizes, int n_in,
                              void* d_out, int out_size, void* d_ws, size_t ws_size,
                              hipStream_t stream) {
    // inputs: 0 query, 1 key, 2 value, 3 Wq, 4 bq, 5 Wk, 6 bk, 7 Wv, 8 bv,
    //         9 fcq_w, 10 fcq_b, 11 fck_w, 12 fck_b
    const float* key   = (const float*)d_in[1];
    const float* value = (const float*)d_in[2];
    const float* Wk    = (const float*)d_in[5];
    const float* Wv    = (const float*)d_in[7];
    const float* bv    = (const float*)d_in[8];
    const float* fckw  = (const float*)d_in[11];

    float* ws   = (float*)d_ws;
    float* u    = ws;            // 1024
    float* num  = ws + 1024;     // 8192
    float* den  = ws + 9216;     // 8
    float* e    = ws + 9224;     // 16384
    float* orow = ws + 25608;    // 8192
    float* out  = (float*)d_out;

    // zero the atomic targets: u + num + den = 9224 floats (~37 KB)
    hipMemsetAsync(ws, 0, 9224 * sizeof(float), stream);

    hipLaunchKernelGGL(k_u,      dim3(64),   dim3(256), 0, stream, Wk, fckw, u);
    hipLaunchKernelGGL(k_scores, dim3(1024), dim3(256), 0, stream, key, u, e, den);
    hipLaunchKernelGGL(k_vbar,   dim3(512),  dim3(256), 0, stream, value, e, num);
    hipLaunchKernelGGL(k_orow,   dim3(2048), dim3(256), 0, stream, Wv, bv, num, den, orow);
    hipLaunchKernelGGL(k_bcast,  dim3(2048), dim3(256), 0, stream, orow, out);
}